// Round 11
// baseline (273.299 us; speedup 1.0000x reference)
//
#include <hip/hip_runtime.h>
#include <hip/hip_bf16.h>

#define T_TOK 8192
#define NEXP 8
#define DMODEL 1024
#define DHID 4096

typedef __bf16 bf16x8_t __attribute__((ext_vector_type(8)));
typedef float f32x4_t __attribute__((ext_vector_type(4)));

#define AS1 __attribute__((address_space(1)))
#define AS3 __attribute__((address_space(3)))

__device__ __forceinline__ unsigned short f2bf(float f) {
    union { float f; unsigned int u; } x;
    x.f = f;
    unsigned int r = x.u + 0x7fffu + ((x.u >> 16) & 1u);  // RNE
    return (unsigned short)(r >> 16);
}

__global__ __launch_bounds__(256) void k_cvt(const float4* __restrict__ in,
                                             ushort4* __restrict__ out, int n4) {
    int i = blockIdx.x * 256 + threadIdx.x;
    if (i >= n4) return;
    float4 v = in[i];
    ushort4 o;
    o.x = f2bf(v.x); o.y = f2bf(v.y); o.z = f2bf(v.z); o.w = f2bf(v.w);
    out[i] = o;
}

__global__ __launch_bounds__(256) void k_transpose_cvt(const float* __restrict__ in,
                                                       unsigned short* __restrict__ out,
                                                       int K, int N) {
    __shared__ float tile[32][33];
    int e = blockIdx.z;
    int k0 = blockIdx.y << 5;
    int n0 = blockIdx.x << 5;
    int t = threadIdx.x;
    int r = t >> 3;
    int c = (t & 7) << 2;
    const float* src = in + ((size_t)e * K + (k0 + r)) * N + n0 + c;
    float4 v = *(const float4*)src;
    tile[r][c + 0] = v.x; tile[r][c + 1] = v.y; tile[r][c + 2] = v.z; tile[r][c + 3] = v.w;
    __syncthreads();
    ushort4 o;
    o.x = f2bf(tile[c + 0][r]);
    o.y = f2bf(tile[c + 1][r]);
    o.z = f2bf(tile[c + 2][r]);
    o.w = f2bf(tile[c + 3][r]);
    unsigned short* dst = out + ((size_t)e * N + (n0 + r)) * K + k0 + c;
    *(ushort4*)dst = o;
}

// ---------------------------------------------------------------------------
// Grouped GEMM, BMxBN tile, BK=64, WMxWN waves (per-wave (BM/WM)x(BN/WN)).
// Proven 2-barrier structure (stage -> sync -> compute -> sync), single LDS
// buffer, strength-reduced addressing, XOR bank swizzle. Confirmed r8->r10:
// runtime scales with L2/L3-level operand traffic -> round 11 cuts traffic:
//   MAP=1 (GEMM1, NTN=16): XCD k owns nt in {2k,2k+1}; consecutive j share
//     the x-slice across the nt-pair and keep B panels L2-resident.
//   MAP=2 (GEMM2, NTN=8): XCD k owns nt=k; the 8 consecutive mt per expert
//     share one 1MB w2t panel -> L2-resident instead of L3 re-fetch.
// ---------------------------------------------------------------------------
template<int K, int N, int BM, int BN, int WM, int WN, int MAP, bool GELU>
__global__ __launch_bounds__(WM * WN * 64) void k_gemm(const unsigned short* __restrict__ A,
                                                       const unsigned short* __restrict__ Bt,
                                                       void* __restrict__ C) {
    constexpr int NTN = N / BN;
    constexpr int T = WM * WN * 64;
    constexpr int ROWS = T / 8;          // rows per global_load_lds issue
    constexpr int NIA = BM / ROWS;
    constexpr int NIB = BN / ROWS;
    constexpr int MF = BM / WM / 16;     // m-frags per wave
    constexpr int NF = BN / WN / 16;     // n-frags per wave
    static_assert(MAP != 1 || NTN == 16, "MAP1 assumes 16 n-tiles");
    static_assert(MAP != 2 || NTN == 8, "MAP2 assumes 8 n-tiles");

    __shared__ __align__(16) char LDS[BM * 128 + BN * 128];

    const int tid = threadIdx.x;
    const int lane = tid & 63;
    const int wid = tid >> 6;
    const int wr = wid / WN;
    const int wc = wid % WN;

    int mt, nt;
    if constexpr (MAP == 1) {
        const int xcd = blockIdx.x & 7;
        const int j = blockIdx.x >> 3;
        nt = 2 * xcd + (j & 1);
        mt = j >> 1;
    } else {
        nt = blockIdx.x & 7;
        mt = blockIdx.x >> 3;
    }
    const int e = (mt * BM) >> 10;       // 1024 tokens per expert

    const char* Aptr = (const char*)(A + (size_t)mt * BM * K);
    const char* Bptr = (const char*)(Bt + ((size_t)e * N + (size_t)nt * BN) * K);

    // K-tile-invariant staging offset (row = tid>>3 within each ROWS group;
    // source col inverse-swizzled; ROWS % 8 == 0 so row&7 == (tid>>3)&7).
    const int goff = (tid >> 3) * (K * 2) + (((tid & 7) << 4) ^ (((tid >> 3) & 7) << 4));

    // K-tile-invariant fragment read bases; frag row ≡ lane&15 (mod 8 == lane&7).
    int preA[2], preB[2];
    #pragma unroll
    for (int kk = 0; kk < 2; ++kk) {
        const int sw = ((kk * 64) + ((lane >> 4) << 4)) ^ ((lane & 7) << 4);
        preA[kk] = wr * ((BM / WM) * 128) + (lane & 15) * 128 + sw;
        preB[kk] = BM * 128 + wc * ((BN / WN) * 128) + (lane & 15) * 128 + sw;
    }

    f32x4_t acc[MF][NF] = {};

    for (int kt = 0; kt < K / 64; ++kt) {
        #pragma unroll
        for (int i = 0; i < NIA; ++i)
            __builtin_amdgcn_global_load_lds(
                (const AS1 void*)(Aptr + (goff + i * (ROWS * K * 2))),
                (AS3 void*)(LDS + i * (ROWS * 128) + tid * 16), 16, 0, 0);
        #pragma unroll
        for (int i = 0; i < NIB; ++i)
            __builtin_amdgcn_global_load_lds(
                (const AS1 void*)(Bptr + (goff + i * (ROWS * K * 2))),
                (AS3 void*)(LDS + BM * 128 + i * (ROWS * 128) + tid * 16), 16, 0, 0);
        Aptr += 128;   // uniform scalar bump: next BK=64 slice
        Bptr += 128;
        __syncthreads();   // vmcnt(0) drain + barrier: tile published
        #pragma unroll
        for (int kk = 0; kk < 2; ++kk) {
            bf16x8_t af[MF], bv[NF];
            #pragma unroll
            for (int m = 0; m < MF; ++m)
                af[m] = *(const bf16x8_t*)(LDS + preA[kk] + m * 2048);
            #pragma unroll
            for (int n = 0; n < NF; ++n)
                bv[n] = *(const bf16x8_t*)(LDS + preB[kk] + n * 2048);
            #pragma unroll
            for (int m = 0; m < MF; ++m)
                #pragma unroll
                for (int n = 0; n < NF; ++n)
                    acc[m][n] = __builtin_amdgcn_mfma_f32_16x16x32_bf16(
                        af[m], bv[n], acc[m][n], 0, 0, 0);
        }
        __syncthreads();   // ds_reads complete before next tile overwrites
    }

    // C/D layout: col = lane&15, row = (lane>>4)*4 + j  [m89/m91]
    const int r0 = mt * BM + wr * (BM / WM) + ((lane >> 4) << 2);
    const int c0 = nt * BN + wc * (BN / WN) + (lane & 15);
    if (GELU) {
        unsigned short* Co = (unsigned short*)C;
        #pragma unroll
        for (int m = 0; m < MF; ++m)
            #pragma unroll
            for (int n = 0; n < NF; ++n)
                #pragma unroll
                for (int j = 0; j < 4; ++j) {
                    float x = acc[m][n][j];
                    float u = 1.5957691216057308f * (x + 0.044715f * x * x * x);
                    float g = x / (1.f + __expf(-u));
                    Co[(size_t)(r0 + m * 16 + j) * N + (c0 + n * 16)] = f2bf(g);
                }
    } else {
        float* Co = (float*)C;
        #pragma unroll
        for (int m = 0; m < MF; ++m)
            #pragma unroll
            for (int n = 0; n < NF; ++n)
                #pragma unroll
                for (int j = 0; j < 4; ++j)
                    Co[(size_t)(r0 + m * 16 + j) * N + (c0 + n * 16)] = acc[m][n][j];
    }
}

extern "C" void kernel_launch(void* const* d_in, const int* in_sizes, int n_in,
                              void* d_out, int out_size, void* d_ws, size_t ws_size,
                              hipStream_t stream) {
    (void)in_sizes; (void)n_in; (void)out_size; (void)ws_size;
    const float* inp = (const float*)d_in[0];
    const float* w1  = (const float*)d_in[1];
    const float* w2  = (const float*)d_in[2];
    float* out = (float*)d_out;

    char* ws = (char*)d_ws;
    unsigned short* wbuf = (unsigned short*)ws;                                 // 64 MB (w1t, then w2t)
    unsigned short* xb   = (unsigned short*)(ws + (size_t)64 * 1024 * 1024);    // 16 MB
    unsigned short* hbuf = (unsigned short*)(ws + (size_t)80 * 1024 * 1024);    // 64 MB

    // 1) x: f32 -> bf16
    k_cvt<<<dim3((T_TOK * DMODEL / 4) / 256), 256, 0, stream>>>(
        (const float4*)inp, (ushort4*)xb, T_TOK * DMODEL / 4);

    // 2) w1 [E][D][H] -> w1t [E][H][D] bf16
    k_transpose_cvt<<<dim3(DHID / 32, DMODEL / 32, NEXP), 256, 0, stream>>>(
        w1, wbuf, DMODEL, DHID);

    // 3) h = gelu(x @ w1[e])  — 256x256, 512 blocks (2/CU), nt-pair per XCD
    k_gemm<DMODEL, DHID, 256, 256, 2, 4, 1, true>
        <<<dim3(512), 512, 0, stream>>>(xb, wbuf, hbuf);

    // 4) w2 [E][H][D] -> w2t [E][D][H] bf16 (reuse wbuf)
    k_transpose_cvt<<<dim3(DMODEL / 32, DHID / 32, NEXP), 256, 0, stream>>>(
        w2, wbuf, DHID, DMODEL);

    // 5) out = h @ w2[e]  — 128x128, 512 blocks, nt pinned per XCD
    k_gemm<DHID, DMODEL, 128, 128, 2, 2, 2, false>
        <<<dim3(512), 256, 0, stream>>>(hbuf, wbuf, out);
}

// Round 12
// 259.026 us; speedup vs baseline: 1.0551x; 1.0551x over previous
//
#include <hip/hip_runtime.h>
#include <hip/hip_bf16.h>

#define T_TOK 8192
#define NEXP 8
#define DMODEL 1024
#define DHID 4096

typedef __bf16 bf16x8_t __attribute__((ext_vector_type(8)));
typedef float f32x4_t __attribute__((ext_vector_type(4)));

#define AS1 __attribute__((address_space(1)))
#define AS3 __attribute__((address_space(3)))

__device__ __forceinline__ unsigned short f2bf(float f) {
    union { float f; unsigned int u; } x;
    x.f = f;
    unsigned int r = x.u + 0x7fffu + ((x.u >> 16) & 1u);  // RNE
    return (unsigned short)(r >> 16);
}

__global__ __launch_bounds__(256) void k_cvt(const float4* __restrict__ in,
                                             ushort4* __restrict__ out, int n4) {
    int i = blockIdx.x * 256 + threadIdx.x;
    if (i >= n4) return;
    float4 v = in[i];
    ushort4 o;
    o.x = f2bf(v.x); o.y = f2bf(v.y); o.z = f2bf(v.z); o.w = f2bf(v.w);
    out[i] = o;
}

__global__ __launch_bounds__(256) void k_transpose_cvt(const float* __restrict__ in,
                                                       unsigned short* __restrict__ out,
                                                       int K, int N) {
    __shared__ float tile[32][33];
    int e = blockIdx.z;
    int k0 = blockIdx.y << 5;
    int n0 = blockIdx.x << 5;
    int t = threadIdx.x;
    int r = t >> 3;
    int c = (t & 7) << 2;
    const float* src = in + ((size_t)e * K + (k0 + r)) * N + n0 + c;
    float4 v = *(const float4*)src;
    tile[r][c + 0] = v.x; tile[r][c + 1] = v.y; tile[r][c + 2] = v.z; tile[r][c + 3] = v.w;
    __syncthreads();
    ushort4 o;
    o.x = f2bf(tile[c + 0][r]);
    o.y = f2bf(tile[c + 1][r]);
    o.z = f2bf(tile[c + 2][r]);
    o.w = f2bf(tile[c + 3][r]);
    unsigned short* dst = out + ((size_t)e * N + (n0 + r)) * K + k0 + c;
    *(ushort4*)dst = o;
}

// ---------------------------------------------------------------------------
// Grouped GEMM, 128x128 tile, BK=64, 4 waves, DOUBLE-BUFFERED 64KB LDS
// (2 blocks/CU). r10/r11 established: time tracks the per-K-tile vmcnt(0)
// drain (3790 cy/CU/K-tile for ~360 cy of work), not HBM bytes and not
// schedule micro-order. This version removes the drain from the critical
// path: tile t+1's 8 loads are issued BEFORE computing tile t; the wait is
// vmcnt(8) (= tile t's loads, issued one full iteration earlier, latency
// hidden behind iteration t-1's compute). Raw s_barrier + explicit
// lgkmcnt(0) — NOT __syncthreads, whose implicit vmcnt(0) would drain the
// in-flight prefetch (the m97 stall).
// WAR safety: stage(t+1) -> buf^1 is issued only after the end-of-(t-1)
// barrier, which follows every wave's lgkmcnt(0) (all ds_reads of buf^1
// from iteration t-1 retired into registers).
// Addressing: r8's strength-reduced K-tile-invariant goff/preA/preB; XOR
// bank swizzle (0 conflicts, r1-r11); bijective XCD block swizzle.
// ---------------------------------------------------------------------------
template<int K, int N, bool GELU>
__global__ __launch_bounds__(256) void k_gemm_db(const unsigned short* __restrict__ A,
                                                 const unsigned short* __restrict__ Bt,
                                                 void* __restrict__ C) {
    constexpr int NTN = N / 128;
    constexpr int NWG = (T_TOK / 128) * NTN;
    constexpr int NKT = K / 64;

    __shared__ __align__(16) char LDS[65536];   // buf b: A at b*32768, B at b*32768+16384

    const int tid = threadIdx.x;
    const int lane = tid & 63;
    const int wid = tid >> 6;
    const int wr = wid >> 1;
    const int wc = wid & 1;

    // bijective XCD swizzle (NWG % 8 == 0)
    const int bid = blockIdx.x;
    const int s = (bid & 7) * (NWG / 8) + (bid >> 3);
    const int nt = s % NTN;
    const int mt = s / NTN;
    const int e = mt >> 3;   // 1024 tokens/expert = 8 row-tiles of 128

    const char* Aptr = (const char*)(A + (size_t)mt * 128 * K);
    const char* Bptr = (const char*)(Bt + ((size_t)e * N + (size_t)nt * 128) * K);

    // K-tile-invariant staging offset: thread stages 16B slot (tid&7) of
    // row (tid>>3) within each 32-row group; source col inverse-swizzled.
    const int goff = (tid >> 3) * (K * 2) + (((tid & 7) << 4) ^ (((tid >> 3) & 7) << 4));

    // K-tile-invariant fragment read bases (relative to buffer base).
    int preA[2], preB[2];
    #pragma unroll
    for (int kk = 0; kk < 2; ++kk) {
        const int sw = ((kk * 64) + ((lane >> 4) << 4)) ^ ((lane & 7) << 4);
        preA[kk] = wr * 8192 + (lane & 15) * 128 + sw;
        preB[kk] = 16384 + wc * 8192 + (lane & 15) * 128 + sw;
    }

    f32x4_t acc[4][4] = {};

    // stage one 64-row K-slice pair (A+B) into buffer `buf`; advances pointers
    auto stage = [&](int buf) {
        #pragma unroll
        for (int i = 0; i < 4; ++i)
            __builtin_amdgcn_global_load_lds(
                (const AS1 void*)(Aptr + (goff + i * (32 * K * 2))),
                (AS3 void*)(LDS + buf * 32768 + i * 4096 + tid * 16), 16, 0, 0);
        #pragma unroll
        for (int i = 0; i < 4; ++i)
            __builtin_amdgcn_global_load_lds(
                (const AS1 void*)(Bptr + (goff + i * (32 * K * 2))),
                (AS3 void*)(LDS + buf * 32768 + 16384 + i * 4096 + tid * 16), 16, 0, 0);
        Aptr += 128;
        Bptr += 128;
    };

    stage(0);   // prologue: tile 0 in flight

    for (int kt = 0; kt < NKT; ++kt) {
        const int cur = kt & 1;
        if (kt + 1 < NKT) {
            stage(cur ^ 1);                                       // prefetch t+1
            asm volatile("s_waitcnt vmcnt(8)" ::: "memory");      // tile t landed
        } else {
            asm volatile("s_waitcnt vmcnt(0)" ::: "memory");
        }
        __builtin_amdgcn_s_barrier();        // all waves: tile t published
        __builtin_amdgcn_sched_barrier(0);

        const char* Lb = LDS + cur * 32768;
        #pragma unroll
        for (int kk = 0; kk < 2; ++kk) {
            bf16x8_t af[4], bv[4];
            #pragma unroll
            for (int m = 0; m < 4; ++m)
                af[m] = *(const bf16x8_t*)(Lb + preA[kk] + m * 2048);
            #pragma unroll
            for (int n = 0; n < 4; ++n)
                bv[n] = *(const bf16x8_t*)(Lb + preB[kk] + n * 2048);
            #pragma unroll
            for (int m = 0; m < 4; ++m)
                #pragma unroll
                for (int n = 0; n < 4; ++n)
                    acc[m][n] = __builtin_amdgcn_mfma_f32_16x16x32_bf16(
                        af[m], bv[n], acc[m][n], 0, 0, 0);
        }

        asm volatile("s_waitcnt lgkmcnt(0)" ::: "memory");   // reads retired
        __builtin_amdgcn_s_barrier();                        // WAR guard for next stage
        __builtin_amdgcn_sched_barrier(0);
    }

    // C/D layout: col = lane&15, row = (lane>>4)*4 + j  [m89/m91]
    const int r0 = mt * 128 + wr * 64 + ((lane >> 4) << 2);
    const int c0 = nt * 128 + wc * 64 + (lane & 15);
    if (GELU) {
        unsigned short* Co = (unsigned short*)C;
        #pragma unroll
        for (int m = 0; m < 4; ++m)
            #pragma unroll
            for (int n = 0; n < 4; ++n)
                #pragma unroll
                for (int j = 0; j < 4; ++j) {
                    float x = acc[m][n][j];
                    float u = 1.5957691216057308f * (x + 0.044715f * x * x * x);
                    float g = x / (1.f + __expf(-u));
                    Co[(size_t)(r0 + m * 16 + j) * N + (c0 + n * 16)] = f2bf(g);
                }
    } else {
        float* Co = (float*)C;
        #pragma unroll
        for (int m = 0; m < 4; ++m)
            #pragma unroll
            for (int n = 0; n < 4; ++n)
                #pragma unroll
                for (int j = 0; j < 4; ++j)
                    Co[(size_t)(r0 + m * 16 + j) * N + (c0 + n * 16)] = acc[m][n][j];
    }
}

extern "C" void kernel_launch(void* const* d_in, const int* in_sizes, int n_in,
                              void* d_out, int out_size, void* d_ws, size_t ws_size,
                              hipStream_t stream) {
    (void)in_sizes; (void)n_in; (void)out_size; (void)ws_size;
    const float* inp = (const float*)d_in[0];
    const float* w1  = (const float*)d_in[1];
    const float* w2  = (const float*)d_in[2];
    float* out = (float*)d_out;

    char* ws = (char*)d_ws;
    unsigned short* wbuf = (unsigned short*)ws;                                 // 64 MB (w1t, then w2t)
    unsigned short* xb   = (unsigned short*)(ws + (size_t)64 * 1024 * 1024);    // 16 MB
    unsigned short* hbuf = (unsigned short*)(ws + (size_t)80 * 1024 * 1024);    // 64 MB

    // 1) x: f32 -> bf16
    k_cvt<<<dim3((T_TOK * DMODEL / 4) / 256), 256, 0, stream>>>(
        (const float4*)inp, (ushort4*)xb, T_TOK * DMODEL / 4);

    // 2) w1 [E][D][H] -> w1t [E][H][D] bf16
    k_transpose_cvt<<<dim3(DHID / 32, DMODEL / 32, NEXP), 256, 0, stream>>>(
        w1, wbuf, DMODEL, DHID);

    // 3) h = gelu(x @ w1[e])  — 2048 blocks, 2/CU, double-buffered pipeline
    k_gemm_db<DMODEL, DHID, true>
        <<<dim3((T_TOK / 128) * (DHID / 128)), 256, 0, stream>>>(xb, wbuf, hbuf);

    // 4) w2 [E][H][D] -> w2t [E][D][H] bf16 (reuse wbuf)
    k_transpose_cvt<<<dim3(DMODEL / 32, DHID / 32, NEXP), 256, 0, stream>>>(
        w2, wbuf, DHID, DMODEL);

    // 5) out = h @ w2[e]  — 512 blocks, 2/CU, double-buffered pipeline
    k_gemm_db<DHID, DMODEL, false>
        <<<dim3((T_TOK / 128) * (DMODEL / 128)), 256, 0, stream>>>(hbuf, wbuf, out);
}

// Round 13
// 245.812 us; speedup vs baseline: 1.1118x; 1.0538x over previous
//
#include <hip/hip_runtime.h>
#include <hip/hip_bf16.h>

#define T_TOK 8192
#define NEXP 8
#define DMODEL 1024
#define DHID 4096

typedef __bf16 bf16x8_t __attribute__((ext_vector_type(8)));
typedef float f32x4_t __attribute__((ext_vector_type(4)));

#define AS1 __attribute__((address_space(1)))
#define AS3 __attribute__((address_space(3)))

__device__ __forceinline__ unsigned short f2bf(float f) {
    union { float f; unsigned int u; } x;
    x.f = f;
    unsigned int r = x.u + 0x7fffu + ((x.u >> 16) & 1u);  // RNE
    return (unsigned short)(r >> 16);
}

__global__ __launch_bounds__(256) void k_cvt(const float4* __restrict__ in,
                                             ushort4* __restrict__ out, int n4) {
    int i = blockIdx.x * 256 + threadIdx.x;
    if (i >= n4) return;
    float4 v = in[i];
    ushort4 o;
    o.x = f2bf(v.x); o.y = f2bf(v.y); o.z = f2bf(v.z); o.w = f2bf(v.w);
    out[i] = o;
}

__global__ __launch_bounds__(256) void k_transpose_cvt(const float* __restrict__ in,
                                                       unsigned short* __restrict__ out,
                                                       int K, int N) {
    __shared__ float tile[32][33];
    int e = blockIdx.z;
    int k0 = blockIdx.y << 5;
    int n0 = blockIdx.x << 5;
    int t = threadIdx.x;
    int r = t >> 3;
    int c = (t & 7) << 2;
    const float* src = in + ((size_t)e * K + (k0 + r)) * N + n0 + c;
    float4 v = *(const float4*)src;
    tile[r][c + 0] = v.x; tile[r][c + 1] = v.y; tile[r][c + 2] = v.z; tile[r][c + 3] = v.w;
    __syncthreads();
    ushort4 o;
    o.x = f2bf(tile[c + 0][r]);
    o.y = f2bf(tile[c + 1][r]);
    o.z = f2bf(tile[c + 2][r]);
    o.w = f2bf(tile[c + 3][r]);
    unsigned short* dst = out + ((size_t)e * N + (n0 + r)) * K + k0 + c;
    *(ushort4*)dst = o;
}

// ---------------------------------------------------------------------------
// Grouped GEMM, BMxBN tile, BK=64, 8 waves (WMxWN grid), 512 threads,
// DOUBLE-BUFFERED LDS with r12's proven no-drain pipeline:
//   stage(t+1) -> vmcnt(NI) [tile t's loads, issued one full iteration ago]
//   -> s_barrier -> compute(buf t) -> lgkmcnt(0) -> s_barrier.
// r6-r12 established delivery is pinned at ~11-18 B/cy/CU regardless of
// schedule; runtime ~ staged_bytes / delivery. Round 13 halves staged bytes:
//   GEMM1: 256x256 (512MB total, was 1.05GB), 128KB LDS, grid 512.
//   GEMM2: 256x128 (768MB total, was 1.05GB), 96KB LDS, grid 256 = 1/CU.
// WAR safety: stage writes buf^1, last read in iter t-1, whose reads retired
// before the end-of-(t-1) lgkmcnt(0)+barrier. Reads of buf t follow this
// iteration's vmcnt+barrier (every wave executes both before any read).
// Addressing: K-tile-invariant goff/preA/preB; XOR bank swizzle (0 conflicts
// r1-r12); bijective XCD block swizzle.
// ---------------------------------------------------------------------------
template<int K, int N, int BM, int BN, int WM, int WN, bool GELU>
__global__ __launch_bounds__(512) void k_gemm_big(const unsigned short* __restrict__ A,
                                                  const unsigned short* __restrict__ Bt,
                                                  void* __restrict__ C) {
    constexpr int TILE = (BM + BN) * 128;     // bytes per K-tile stage
    constexpr int IA = BM / 64;               // A issues (8KB each, 512 thr x 16B)
    constexpr int IB = BN / 64;
    constexpr int NI = IA + IB;
    constexpr int NKT = K / 64;
    constexpr int MF = BM / WM / 16;
    constexpr int NF = BN / WN / 16;
    constexpr int NTN = N / BN;
    constexpr int NWG = (T_TOK / BM) * NTN;

    __shared__ __align__(16) char LDS[2 * TILE];

    const int tid = threadIdx.x;
    const int lane = tid & 63;
    const int wid = tid >> 6;
    const int wr = wid / WN;
    const int wc = wid % WN;

    // bijective XCD swizzle (NWG % 8 == 0)
    const int bid = blockIdx.x;
    const int s = (bid & 7) * (NWG / 8) + (bid >> 3);
    const int nt = s % NTN;
    const int mt = s / NTN;
    const int e = (mt * BM) >> 10;            // 1024 tokens per expert

    const char* Aptr = (const char*)(A + (size_t)mt * BM * K);
    const char* Bptr = (const char*)(Bt + ((size_t)e * N + (size_t)nt * BN) * K);

    // K-tile-invariant staging offset: thread stages 16B slot (tid&7) of
    // row (tid>>3) within each 64-row group; source col inverse-swizzled.
    const int goff = (tid >> 3) * (K * 2) + (((tid & 7) << 4) ^ (((tid >> 3) & 7) << 4));

    // K-tile-invariant fragment read bases (relative to buffer base).
    int preA[2], preB[2];
    #pragma unroll
    for (int kk = 0; kk < 2; ++kk) {
        const int sw = ((kk * 64) + ((lane >> 4) << 4)) ^ ((lane & 7) << 4);
        preA[kk] = wr * ((BM / WM) * 128) + (lane & 15) * 128 + sw;
        preB[kk] = BM * 128 + wc * ((BN / WN) * 128) + (lane & 15) * 128 + sw;
    }

    f32x4_t acc[MF][NF] = {};

    auto stage = [&](int buf) {
        #pragma unroll
        for (int i = 0; i < IA; ++i)
            __builtin_amdgcn_global_load_lds(
                (const AS1 void*)(Aptr + (goff + i * (64 * K * 2))),
                (AS3 void*)(LDS + buf * TILE + i * 8192 + tid * 16), 16, 0, 0);
        #pragma unroll
        for (int i = 0; i < IB; ++i)
            __builtin_amdgcn_global_load_lds(
                (const AS1 void*)(Bptr + (goff + i * (64 * K * 2))),
                (AS3 void*)(LDS + buf * TILE + BM * 128 + i * 8192 + tid * 16), 16, 0, 0);
        Aptr += 128;
        Bptr += 128;
    };

    stage(0);   // prologue: tile 0 in flight

    for (int kt = 0; kt < NKT; ++kt) {
        const int cur = kt & 1;
        if (kt + 1 < NKT) {
            stage(cur ^ 1);                   // prefetch t+1 (keeps pipe streaming)
            if constexpr (NI == 8)
                asm volatile("s_waitcnt vmcnt(8)" ::: "memory");
            else
                asm volatile("s_waitcnt vmcnt(6)" ::: "memory");
        } else {
            asm volatile("s_waitcnt vmcnt(0)" ::: "memory");
        }
        __builtin_amdgcn_s_barrier();         // tile t published to all waves
        __builtin_amdgcn_sched_barrier(0);

        const char* Lb = LDS + cur * TILE;
        #pragma unroll
        for (int kk = 0; kk < 2; ++kk) {
            bf16x8_t af[MF], bv[NF];
            #pragma unroll
            for (int m = 0; m < MF; ++m)
                af[m] = *(const bf16x8_t*)(Lb + preA[kk] + m * 2048);
            #pragma unroll
            for (int n = 0; n < NF; ++n)
                bv[n] = *(const bf16x8_t*)(Lb + preB[kk] + n * 2048);
            #pragma unroll
            for (int m = 0; m < MF; ++m)
                #pragma unroll
                for (int n = 0; n < NF; ++n)
                    acc[m][n] = __builtin_amdgcn_mfma_f32_16x16x32_bf16(
                        af[m], bv[n], acc[m][n], 0, 0, 0);
        }

        asm volatile("s_waitcnt lgkmcnt(0)" ::: "memory");  // reads retired
        __builtin_amdgcn_s_barrier();                       // WAR guard
        __builtin_amdgcn_sched_barrier(0);
    }

    // C/D layout: col = lane&15, row = (lane>>4)*4 + j  [m89/m91]
    const int r0 = mt * BM + wr * (BM / WM) + ((lane >> 4) << 2);
    const int c0 = nt * BN + wc * (BN / WN) + (lane & 15);
    if (GELU) {
        unsigned short* Co = (unsigned short*)C;
        #pragma unroll
        for (int m = 0; m < MF; ++m)
            #pragma unroll
            for (int n = 0; n < NF; ++n)
                #pragma unroll
                for (int j = 0; j < 4; ++j) {
                    float x = acc[m][n][j];
                    float u = 1.5957691216057308f * (x + 0.044715f * x * x * x);
                    float g = x / (1.f + __expf(-u));
                    Co[(size_t)(r0 + m * 16 + j) * N + (c0 + n * 16)] = f2bf(g);
                }
    } else {
        float* Co = (float*)C;
        #pragma unroll
        for (int m = 0; m < MF; ++m)
            #pragma unroll
            for (int n = 0; n < NF; ++n)
                #pragma unroll
                for (int j = 0; j < 4; ++j)
                    Co[(size_t)(r0 + m * 16 + j) * N + (c0 + n * 16)] = acc[m][n][j];
    }
}

extern "C" void kernel_launch(void* const* d_in, const int* in_sizes, int n_in,
                              void* d_out, int out_size, void* d_ws, size_t ws_size,
                              hipStream_t stream) {
    (void)in_sizes; (void)n_in; (void)out_size; (void)ws_size;
    const float* inp = (const float*)d_in[0];
    const float* w1  = (const float*)d_in[1];
    const float* w2  = (const float*)d_in[2];
    float* out = (float*)d_out;

    char* ws = (char*)d_ws;
    unsigned short* wbuf = (unsigned short*)ws;                                 // 64 MB (w1t, then w2t)
    unsigned short* xb   = (unsigned short*)(ws + (size_t)64 * 1024 * 1024);    // 16 MB
    unsigned short* hbuf = (unsigned short*)(ws + (size_t)80 * 1024 * 1024);    // 64 MB

    // 1) x: f32 -> bf16
    k_cvt<<<dim3((T_TOK * DMODEL / 4) / 256), 256, 0, stream>>>(
        (const float4*)inp, (ushort4*)xb, T_TOK * DMODEL / 4);

    // 2) w1 [E][D][H] -> w1t [E][H][D] bf16
    k_transpose_cvt<<<dim3(DHID / 32, DMODEL / 32, NEXP), 256, 0, stream>>>(
        w1, wbuf, DMODEL, DHID);

    // 3) h = gelu(x @ w1[e])  — 256x256, 128KB dbuf LDS, 512 blocks
    k_gemm_big<DMODEL, DHID, 256, 256, 2, 4, true>
        <<<dim3(512), 512, 0, stream>>>(xb, wbuf, hbuf);

    // 4) w2 [E][H][D] -> w2t [E][D][H] bf16 (reuse wbuf)
    k_transpose_cvt<<<dim3(DMODEL / 32, DHID / 32, NEXP), 256, 0, stream>>>(
        w2, wbuf, DHID, DMODEL);

    // 5) out = h @ w2[e]  — 256x128, 96KB dbuf LDS, 256 blocks = 1/CU
    k_gemm_big<DHID, DMODEL, 256, 128, 4, 2, false>
        <<<dim3(256), 512, 0, stream>>>(hbuf, wbuf, out);
}

// Round 14
// 244.673 us; speedup vs baseline: 1.1170x; 1.0047x over previous
//
#include <hip/hip_runtime.h>
#include <hip/hip_bf16.h>

#define T_TOK 8192
#define NEXP 8
#define DMODEL 1024
#define DHID 4096

typedef __bf16 bf16x8_t __attribute__((ext_vector_type(8)));
typedef float f32x4_t __attribute__((ext_vector_type(4)));

#define AS1 __attribute__((address_space(1)))
#define AS3 __attribute__((address_space(3)))

__device__ __forceinline__ unsigned short f2bf(float f) {
    union { float f; unsigned int u; } x;
    x.f = f;
    unsigned int r = x.u + 0x7fffu + ((x.u >> 16) & 1u);  // RNE
    return (unsigned short)(r >> 16);
}

__global__ __launch_bounds__(256) void k_cvt(const float4* __restrict__ in,
                                             ushort4* __restrict__ out, int n4) {
    int i = blockIdx.x * 256 + threadIdx.x;
    if (i >= n4) return;
    float4 v = in[i];
    ushort4 o;
    o.x = f2bf(v.x); o.y = f2bf(v.y); o.z = f2bf(v.z); o.w = f2bf(v.w);
    out[i] = o;
}

__global__ __launch_bounds__(256) void k_transpose_cvt(const float* __restrict__ in,
                                                       unsigned short* __restrict__ out,
                                                       int K, int N) {
    __shared__ float tile[32][33];
    int e = blockIdx.z;
    int k0 = blockIdx.y << 5;
    int n0 = blockIdx.x << 5;
    int t = threadIdx.x;
    int r = t >> 3;
    int c = (t & 7) << 2;
    const float* src = in + ((size_t)e * K + (k0 + r)) * N + n0 + c;
    float4 v = *(const float4*)src;
    tile[r][c + 0] = v.x; tile[r][c + 1] = v.y; tile[r][c + 2] = v.z; tile[r][c + 3] = v.w;
    __syncthreads();
    ushort4 o;
    o.x = f2bf(tile[c + 0][r]);
    o.y = f2bf(tile[c + 1][r]);
    o.z = f2bf(tile[c + 2][r]);
    o.w = f2bf(tile[c + 3][r]);
    unsigned short* dst = out + ((size_t)e * N + (n0 + r)) * K + k0 + c;
    *(ushort4*)dst = o;
}

// ---------------------------------------------------------------------------
// Grouped GEMM, BMxBN tile, BK=64, 8 waves (WMxWN grid), 512 threads,
// DOUBLE-BUFFERED LDS with r12's proven no-drain pipeline:
//   stage(t+1) -> vmcnt(NI) [tile t's loads, issued one full iteration ago]
//   -> s_barrier -> compute(buf t) -> lgkmcnt(0) -> s_barrier.
// r6-r12 established delivery is pinned at ~11-18 B/cy/CU regardless of
// schedule; runtime ~ staged_bytes / delivery. Round 13 halves staged bytes:
//   GEMM1: 256x256 (512MB total, was 1.05GB), 128KB LDS, grid 512.
//   GEMM2: 256x128 (768MB total, was 1.05GB), 96KB LDS, grid 256 = 1/CU.
// WAR safety: stage writes buf^1, last read in iter t-1, whose reads retired
// before the end-of-(t-1) lgkmcnt(0)+barrier. Reads of buf t follow this
// iteration's vmcnt+barrier (every wave executes both before any read).
// Addressing: K-tile-invariant goff/preA/preB; XOR bank swizzle (0 conflicts
// r1-r12); bijective XCD block swizzle.
// ---------------------------------------------------------------------------
template<int K, int N, int BM, int BN, int WM, int WN, bool GELU>
__global__ __launch_bounds__(512) void k_gemm_big(const unsigned short* __restrict__ A,
                                                  const unsigned short* __restrict__ Bt,
                                                  void* __restrict__ C) {
    constexpr int TILE = (BM + BN) * 128;     // bytes per K-tile stage
    constexpr int IA = BM / 64;               // A issues (8KB each, 512 thr x 16B)
    constexpr int IB = BN / 64;
    constexpr int NI = IA + IB;
    constexpr int NKT = K / 64;
    constexpr int MF = BM / WM / 16;
    constexpr int NF = BN / WN / 16;
    constexpr int NTN = N / BN;
    constexpr int NWG = (T_TOK / BM) * NTN;

    __shared__ __align__(16) char LDS[2 * TILE];

    const int tid = threadIdx.x;
    const int lane = tid & 63;
    const int wid = tid >> 6;
    const int wr = wid / WN;
    const int wc = wid % WN;

    // bijective XCD swizzle (NWG % 8 == 0)
    const int bid = blockIdx.x;
    const int s = (bid & 7) * (NWG / 8) + (bid >> 3);
    const int nt = s % NTN;
    const int mt = s / NTN;
    const int e = (mt * BM) >> 10;            // 1024 tokens per expert

    const char* Aptr = (const char*)(A + (size_t)mt * BM * K);
    const char* Bptr = (const char*)(Bt + ((size_t)e * N + (size_t)nt * BN) * K);

    // K-tile-invariant staging offset: thread stages 16B slot (tid&7) of
    // row (tid>>3) within each 64-row group; source col inverse-swizzled.
    const int goff = (tid >> 3) * (K * 2) + (((tid & 7) << 4) ^ (((tid >> 3) & 7) << 4));

    // K-tile-invariant fragment read bases (relative to buffer base).
    int preA[2], preB[2];
    #pragma unroll
    for (int kk = 0; kk < 2; ++kk) {
        const int sw = ((kk * 64) + ((lane >> 4) << 4)) ^ ((lane & 7) << 4);
        preA[kk] = wr * ((BM / WM) * 128) + (lane & 15) * 128 + sw;
        preB[kk] = BM * 128 + wc * ((BN / WN) * 128) + (lane & 15) * 128 + sw;
    }

    f32x4_t acc[MF][NF] = {};

    auto stage = [&](int buf) {
        #pragma unroll
        for (int i = 0; i < IA; ++i)
            __builtin_amdgcn_global_load_lds(
                (const AS1 void*)(Aptr + (goff + i * (64 * K * 2))),
                (AS3 void*)(LDS + buf * TILE + i * 8192 + tid * 16), 16, 0, 0);
        #pragma unroll
        for (int i = 0; i < IB; ++i)
            __builtin_amdgcn_global_load_lds(
                (const AS1 void*)(Bptr + (goff + i * (64 * K * 2))),
                (AS3 void*)(LDS + buf * TILE + BM * 128 + i * 8192 + tid * 16), 16, 0, 0);
        Aptr += 128;
        Bptr += 128;
    };

    stage(0);   // prologue: tile 0 in flight

    for (int kt = 0; kt < NKT; ++kt) {
        const int cur = kt & 1;
        if (kt + 1 < NKT) {
            stage(cur ^ 1);                   // prefetch t+1 (keeps pipe streaming)
            if constexpr (NI == 8)
                asm volatile("s_waitcnt vmcnt(8)" ::: "memory");
            else
                asm volatile("s_waitcnt vmcnt(6)" ::: "memory");
        } else {
            asm volatile("s_waitcnt vmcnt(0)" ::: "memory");
        }
        __builtin_amdgcn_s_barrier();         // tile t published to all waves
        __builtin_amdgcn_sched_barrier(0);

        const char* Lb = LDS + cur * TILE;
        #pragma unroll
        for (int kk = 0; kk < 2; ++kk) {
            bf16x8_t af[MF], bv[NF];
            #pragma unroll
            for (int m = 0; m < MF; ++m)
                af[m] = *(const bf16x8_t*)(Lb + preA[kk] + m * 2048);
            #pragma unroll
            for (int n = 0; n < NF; ++n)
                bv[n] = *(const bf16x8_t*)(Lb + preB[kk] + n * 2048);
            #pragma unroll
            for (int m = 0; m < MF; ++m)
                #pragma unroll
                for (int n = 0; n < NF; ++n)
                    acc[m][n] = __builtin_amdgcn_mfma_f32_16x16x32_bf16(
                        af[m], bv[n], acc[m][n], 0, 0, 0);
        }

        asm volatile("s_waitcnt lgkmcnt(0)" ::: "memory");  // reads retired
        __builtin_amdgcn_s_barrier();                       // WAR guard
        __builtin_amdgcn_sched_barrier(0);
    }

    // C/D layout: col = lane&15, row = (lane>>4)*4 + j  [m89/m91]
    const int r0 = mt * BM + wr * (BM / WM) + ((lane >> 4) << 2);
    const int c0 = nt * BN + wc * (BN / WN) + (lane & 15);
    if (GELU) {
        unsigned short* Co = (unsigned short*)C;
        #pragma unroll
        for (int m = 0; m < MF; ++m)
            #pragma unroll
            for (int n = 0; n < NF; ++n)
                #pragma unroll
                for (int j = 0; j < 4; ++j) {
                    float x = acc[m][n][j];
                    float u = 1.5957691216057308f * (x + 0.044715f * x * x * x);
                    float g = x / (1.f + __expf(-u));
                    Co[(size_t)(r0 + m * 16 + j) * N + (c0 + n * 16)] = f2bf(g);
                }
    } else {
        float* Co = (float*)C;
        #pragma unroll
        for (int m = 0; m < MF; ++m)
            #pragma unroll
            for (int n = 0; n < NF; ++n)
                #pragma unroll
                for (int j = 0; j < 4; ++j)
                    Co[(size_t)(r0 + m * 16 + j) * N + (c0 + n * 16)] = acc[m][n][j];
    }
}

extern "C" void kernel_launch(void* const* d_in, const int* in_sizes, int n_in,
                              void* d_out, int out_size, void* d_ws, size_t ws_size,
                              hipStream_t stream) {
    (void)in_sizes; (void)n_in; (void)out_size; (void)ws_size;
    const float* inp = (const float*)d_in[0];
    const float* w1  = (const float*)d_in[1];
    const float* w2  = (const float*)d_in[2];
    float* out = (float*)d_out;

    char* ws = (char*)d_ws;
    unsigned short* wbuf = (unsigned short*)ws;                                 // 64 MB (w1t, then w2t)
    unsigned short* xb   = (unsigned short*)(ws + (size_t)64 * 1024 * 1024);    // 16 MB
    unsigned short* hbuf = (unsigned short*)(ws + (size_t)80 * 1024 * 1024);    // 64 MB

    // 1) x: f32 -> bf16
    k_cvt<<<dim3((T_TOK * DMODEL / 4) / 256), 256, 0, stream>>>(
        (const float4*)inp, (ushort4*)xb, T_TOK * DMODEL / 4);

    // 2) w1 [E][D][H] -> w1t [E][H][D] bf16
    k_transpose_cvt<<<dim3(DHID / 32, DMODEL / 32, NEXP), 256, 0, stream>>>(
        w1, wbuf, DMODEL, DHID);

    // 3) h = gelu(x @ w1[e])  — 256x256, 128KB dbuf LDS, 512 blocks
    k_gemm_big<DMODEL, DHID, 256, 256, 2, 4, true>
        <<<dim3(512), 512, 0, stream>>>(xb, wbuf, hbuf);

    // 4) w2 [E][H][D] -> w2t [E][D][H] bf16 (reuse wbuf)
    k_transpose_cvt<<<dim3(DMODEL / 32, DHID / 32, NEXP), 256, 0, stream>>>(
        w2, wbuf, DHID, DMODEL);

    // 5) out = h @ w2[e]  — 256x128, 96KB dbuf LDS, 256 blocks = 1/CU
    k_gemm_big<DHID, DMODEL, 256, 128, 4, 2, false>
        <<<dim3(256), 512, 0, stream>>>(hbuf, wbuf, out);
}